// Round 1
// baseline (80.869 us; speedup 1.0000x reference)
//
#include <hip/hip_runtime.h>

#define BATCH  8192
#define GROUPS 512
#define OUT_D  8

// Each thread handles one batch row x 4 consecutive groups:
//   reads 12 contiguous floats (3x float4, 48B-aligned),
//   writes 32 contiguous floats (8x float4).
__global__ __launch_bounds__(256) void hoact_kernel(
    const float* __restrict__ X,
    const float* __restrict__ P,
    float* __restrict__ out)
{
    const int GP = GROUPS / 4;  // group-quads per batch row
    int t = blockIdx.x * blockDim.x + threadIdx.x;
    if (t >= BATCH * GP) return;
    int b  = t / GP;
    int g0 = (t % GP) * 4;

    const float* xp = X + (size_t)b * (GROUPS * 3) + (size_t)g0 * 3;
    float4 v0 = *(const float4*)(xp + 0);
    float4 v1 = *(const float4*)(xp + 4);
    float4 v2 = *(const float4*)(xp + 8);
    float a[12] = {v0.x, v0.y, v0.z, v0.w,
                   v1.x, v1.y, v1.z, v1.w,
                   v2.x, v2.y, v2.z, v2.w};

    float* op = out + ((size_t)b * GROUPS + g0) * OUT_D;

    #pragma unroll
    for (int gi = 0; gi < 4; ++gi) {
        float x0 = a[gi*3+0], x1 = a[gi*3+1], x2 = a[gi*3+2];
        float b0 = fabsf(x0), b1 = fabsf(x1), b2 = fabsf(x2);
        // term value = sign * 3^orig_index
        int t0 = (x0 >= 0.f) ? 1 : -1;
        int t1 = (x1 >= 0.f) ? 3 : -3;
        int t2 = (x2 >= 0.f) ? 9 : -9;
        // sort ascending by abs (3-element network; ties don't affect result)
        if (b0 > b1) { float tb=b0; b0=b1; b1=tb; int tt=t0; t0=t1; t1=tt; }
        if (b1 > b2) { float tb=b1; b1=b2; b2=tb; int tt=t1; t1=t2; t2=tt; }
        if (b0 > b1) { float tb=b0; b0=b1; b1=tb; int tt=t0; t0=t1; t1=tt; }
        // suffix sums + center offset 13
        int i2 = t2 + 13;
        int i1 = t1 + t2 + 13;
        int i0 = t0 + t1 + t2 + 13;
        // simplex interpolation coefficients
        float c0 = b0;
        float c1 = b1 - b0;
        float c2 = b2 - b1;

        const float* pg = P + (size_t)(g0 + gi) * (27 * OUT_D);
        const float4* p0 = (const float4*)(pg + i0 * OUT_D);
        const float4* p1 = (const float4*)(pg + i1 * OUT_D);
        const float4* p2 = (const float4*)(pg + i2 * OUT_D);
        float4 q0l = p0[0], q0h = p0[1];
        float4 q1l = p1[0], q1h = p1[1];
        float4 q2l = p2[0], q2h = p2[1];

        float4 lo, hi;
        lo.x = c0*q0l.x + c1*q1l.x + c2*q2l.x;
        lo.y = c0*q0l.y + c1*q1l.y + c2*q2l.y;
        lo.z = c0*q0l.z + c1*q1l.z + c2*q2l.z;
        lo.w = c0*q0l.w + c1*q1l.w + c2*q2l.w;
        hi.x = c0*q0h.x + c1*q1h.x + c2*q2h.x;
        hi.y = c0*q0h.y + c1*q1h.y + c2*q2h.y;
        hi.z = c0*q0h.z + c1*q1h.z + c2*q2h.z;
        hi.w = c0*q0h.w + c1*q1h.w + c2*q2h.w;

        *(float4*)(op + gi*OUT_D + 0) = lo;
        *(float4*)(op + gi*OUT_D + 4) = hi;
    }
}

extern "C" void kernel_launch(void* const* d_in, const int* in_sizes, int n_in,
                              void* d_out, int out_size, void* d_ws, size_t ws_size,
                              hipStream_t stream) {
    const float* X = (const float*)d_in[0];
    const float* P = (const float*)d_in[1];
    float* out = (float*)d_out;

    const int total_threads = BATCH * (GROUPS / 4);   // 1,048,576
    const int block = 256;
    const int grid = (total_threads + block - 1) / block;  // 4096
    hoact_kernel<<<grid, block, 0, stream>>>(X, P, out);
}

// Round 2
// 50.599 us; speedup vs baseline: 1.5982x; 1.5982x over previous
//
#include <hip/hip_runtime.h>

#define BATCH  8192
#define GROUPS 512
#define OUT_D  8
#define BT     64     // batch rows per block (= lanes per wave)
#define GT     16     // groups per block (4 waves x 4 groups)
#define ROWU   33     // 16B units per LDS row: 32 data + 1 pad (uniform bank slots)

// Block = 256 threads = 4 waves. Wave w handles groups gbase..gbase+3 for 64
// consecutive batch rows (lane = batch row). All 64 lanes of a gather
// instruction hit the SAME group's 864B param region -> ~14 L2 lines/instr
// instead of 64. Output tile staged in LDS, then written with lanes
// contiguous along the group axis -> full-line HBM writes.
__global__ __launch_bounds__(256) void hoact_kernel(
    const float* __restrict__ X,
    const float* __restrict__ P,
    float* __restrict__ out)
{
    __shared__ float4 lds[BT * ROWU];   // 64*33*16B = 33 KB

    const int nbt = BATCH / BT;         // 128 batch tiles
    const int bt = blockIdx.x % nbt;
    const int gt = blockIdx.x / nbt;    // 32 group tiles

    const int lane = threadIdx.x & 63;
    const int w    = threadIdx.x >> 6;  // wave id 0..3

    const int b     = bt * BT + lane;
    const int gbase = gt * GT + w * 4;

    // 12 contiguous floats: groups gbase..gbase+3 of row b (16B-aligned)
    const float* xp = X + (size_t)b * (GROUPS * 3) + (size_t)gbase * 3;
    float4 v0 = *(const float4*)(xp + 0);
    float4 v1 = *(const float4*)(xp + 4);
    float4 v2 = *(const float4*)(xp + 8);
    float a[12] = {v0.x, v0.y, v0.z, v0.w,
                   v1.x, v1.y, v1.z, v1.w,
                   v2.x, v2.y, v2.z, v2.w};

    #pragma unroll
    for (int gi = 0; gi < 4; ++gi) {
        float x0 = a[gi*3+0], x1 = a[gi*3+1], x2 = a[gi*3+2];
        float b0 = fabsf(x0), b1 = fabsf(x1), b2 = fabsf(x2);
        int t0 = (x0 >= 0.f) ? 1 : -1;
        int t1 = (x1 >= 0.f) ? 3 : -3;
        int t2 = (x2 >= 0.f) ? 9 : -9;
        // sort ascending by |x| (ties don't affect the result)
        if (b0 > b1) { float tb=b0; b0=b1; b1=tb; int tt=t0; t0=t1; t1=tt; }
        if (b1 > b2) { float tb=b1; b1=b2; b2=tb; int tt=t1; t1=t2; t2=tt; }
        if (b0 > b1) { float tb=b0; b0=b1; b1=tb; int tt=t0; t0=t1; t1=tt; }
        int i2 = t2 + 13;
        int i1 = t1 + t2 + 13;
        int i0 = t0 + t1 + t2 + 13;
        float c0 = b0;
        float c1 = b1 - b0;
        float c2 = b2 - b1;

        // all lanes share group g -> gathers coalesce within 864B region
        const float* pg = P + (size_t)(gbase + gi) * (27 * OUT_D);
        const float4* p0 = (const float4*)(pg + i0 * OUT_D);
        const float4* p1 = (const float4*)(pg + i1 * OUT_D);
        const float4* p2 = (const float4*)(pg + i2 * OUT_D);
        float4 q0l = p0[0], q0h = p0[1];
        float4 q1l = p1[0], q1h = p1[1];
        float4 q2l = p2[0], q2h = p2[1];

        float4 lo, hi;
        lo.x = c0*q0l.x + c1*q1l.x + c2*q2l.x;
        lo.y = c0*q0l.y + c1*q1l.y + c2*q2l.y;
        lo.z = c0*q0l.z + c1*q1l.z + c2*q2l.z;
        lo.w = c0*q0l.w + c1*q1l.w + c2*q2l.w;
        hi.x = c0*q0h.x + c1*q1h.x + c2*q2h.x;
        hi.y = c0*q0h.y + c1*q1h.y + c2*q2h.y;
        hi.z = c0*q0h.z + c1*q1h.z + c2*q2h.z;
        hi.w = c0*q0h.w + c1*q1h.w + c2*q2h.w;

        // LDS row = lane (batch row), col unit = (group-in-tile)*2 + half
        int f0 = (w * 4 + gi) * 2;
        lds[lane * ROWU + f0 + 0] = lo;
        lds[lane * ROWU + f0 + 1] = hi;
    }

    __syncthreads();

    // Write 64 rows x 128 floats: lanes contiguous along group axis ->
    // each wave store instruction covers 1KB of contiguous HBM (full lines).
    float4* out4 = (float4*)out;
    const size_t row_u = GROUPS * OUT_D / 4;       // 1024 float4 per out row
    const size_t col0  = (size_t)gt * GT * OUT_D / 4;  // 32-unit col offset
    #pragma unroll
    for (int k = 0; k < 8; ++k) {
        int u = threadIdx.x + 256 * k;   // 0..2047
        int r = u >> 5;                  // LDS row 0..63
        int f = u & 31;                  // col unit 0..31
        float4 val = lds[r * ROWU + f];
        out4[(size_t)(bt * BT + r) * row_u + col0 + f] = val;
    }
}

extern "C" void kernel_launch(void* const* d_in, const int* in_sizes, int n_in,
                              void* d_out, int out_size, void* d_ws, size_t ws_size,
                              hipStream_t stream) {
    const float* X = (const float*)d_in[0];
    const float* P = (const float*)d_in[1];
    float* out = (float*)d_out;

    const int grid = (BATCH / BT) * (GROUPS / GT);  // 128 * 32 = 4096
    hoact_kernel<<<grid, 256, 0, stream>>>(X, P, out);
}

// Round 3
// 49.337 us; speedup vs baseline: 1.6391x; 1.0256x over previous
//
#include <hip/hip_runtime.h>

#define BATCH  8192
#define GROUPS 512
#define OUT_D  8
#define BT     64     // batch rows per block (= lanes per wave)
#define GT     16     // groups per block (4 waves x 4 groups)
#define ROWU   33     // float4 units per out-staging row: 32 data + 1 pad

// Block = 256 threads = 4 waves. Wave w handles groups gt*16+w*4 .. +3 for 64
// consecutive batch rows (lane = batch row): every param-gather instruction's
// 64 lanes hit the SAME group's 864B region (~13 lines, not 64).
// X ingress is transposed through LDS so the global loads are coalesced
// (thread wants a row-segment, wave wants a column). Output tile staged in
// LDS and written with lanes contiguous along the group axis (full lines).
// The 33KB LDS buffer is reused for X staging then output staging.
__global__ __launch_bounds__(256) void hoact_kernel(
    const float* __restrict__ X,
    const float* __restrict__ P,
    float* __restrict__ out)
{
    __shared__ float4 buf[BT * ROWU];    // 33 KB
    float* xs = (float*)buf;             // phase 0/1a layout: xs[c*65 + r], c<48, r<64

    const int nbt = BATCH / BT;          // 128 batch tiles
    const int bt = blockIdx.x % nbt;
    const int gt = blockIdx.x / nbt;     // 32 group tiles

    const int lane = threadIdx.x & 63;
    const int w    = threadIdx.x >> 6;   // wave id 0..3

    // ---- phase 0: coalesced X tile load + transpose into LDS ----
    // tile = rows bt*64.., cols gt*48.. (48 floats = 12 float4 per row)
    const float4* X4 = (const float4*)X;
    const size_t xrow_u = GROUPS * 3 / 4;            // 384 float4 per X row
    #pragma unroll
    for (int k = 0; k < 3; ++k) {
        int m  = threadIdx.x + 256 * k;              // 0..767
        int r  = m / 12;
        int c4 = m % 12;
        float4 v = X4[(size_t)(bt * BT + r) * xrow_u + (size_t)gt * 12 + c4];
        xs[(c4 * 4 + 0) * 65 + r] = v.x;
        xs[(c4 * 4 + 1) * 65 + r] = v.y;
        xs[(c4 * 4 + 2) * 65 + r] = v.z;
        xs[(c4 * 4 + 3) * 65 + r] = v.w;
    }
    __syncthreads();

    // ---- phase 1a: pull this thread's 12 X values (bank-conflict-free) ----
    float a[12];
    #pragma unroll
    for (int c = 0; c < 12; ++c)
        a[c] = xs[(w * 12 + c) * 65 + lane];
    __syncthreads();    // xs dead; buf becomes output staging

    // ---- phase 1b: compute + stage output ----
    const int gbase = gt * GT + w * 4;
    #pragma unroll
    for (int gi = 0; gi < 4; ++gi) {
        float x0 = a[gi*3+0], x1 = a[gi*3+1], x2 = a[gi*3+2];
        float b0 = fabsf(x0), b1 = fabsf(x1), b2 = fabsf(x2);
        int t0 = (x0 >= 0.f) ? 1 : -1;
        int t1 = (x1 >= 0.f) ? 3 : -3;
        int t2 = (x2 >= 0.f) ? 9 : -9;
        // sort ascending by |x| (ties don't affect the result)
        if (b0 > b1) { float tb=b0; b0=b1; b1=tb; int tt=t0; t0=t1; t1=tt; }
        if (b1 > b2) { float tb=b1; b1=b2; b2=tb; int tt=t1; t1=t2; t2=tt; }
        if (b0 > b1) { float tb=b0; b0=b1; b1=tb; int tt=t0; t0=t1; t1=tt; }
        int i2 = t2 + 13;
        int i1 = t1 + t2 + 13;
        int i0 = t0 + t1 + t2 + 13;
        float c0 = b0;
        float c1 = b1 - b0;
        float c2 = b2 - b1;

        // all 64 lanes share this group -> gathers stay within one 864B region
        const float* pg = P + (size_t)(gbase + gi) * (27 * OUT_D);
        const float4* p0 = (const float4*)(pg + i0 * OUT_D);
        const float4* p1 = (const float4*)(pg + i1 * OUT_D);
        const float4* p2 = (const float4*)(pg + i2 * OUT_D);
        float4 q0l = p0[0], q0h = p0[1];
        float4 q1l = p1[0], q1h = p1[1];
        float4 q2l = p2[0], q2h = p2[1];

        float4 lo, hi;
        lo.x = c0*q0l.x + c1*q1l.x + c2*q2l.x;
        lo.y = c0*q0l.y + c1*q1l.y + c2*q2l.y;
        lo.z = c0*q0l.z + c1*q1l.z + c2*q2l.z;
        lo.w = c0*q0l.w + c1*q1l.w + c2*q2l.w;
        hi.x = c0*q0h.x + c1*q1h.x + c2*q2h.x;
        hi.y = c0*q0h.y + c1*q1h.y + c2*q2h.y;
        hi.z = c0*q0h.z + c1*q1h.z + c2*q2h.z;
        hi.w = c0*q0h.w + c1*q1h.w + c2*q2h.w;

        int f0 = (w * 4 + gi) * 2;
        buf[lane * ROWU + f0 + 0] = lo;
        buf[lane * ROWU + f0 + 1] = hi;
    }
    __syncthreads();

    // ---- phase 2: store 64 rows x 128 floats, lanes contiguous along group ----
    float4* out4 = (float4*)out;
    const size_t row_u = GROUPS * OUT_D / 4;            // 1024 float4 per out row
    const size_t col0  = (size_t)gt * GT * OUT_D / 4;   // 32-unit col offset
    #pragma unroll
    for (int k = 0; k < 8; ++k) {
        int u = threadIdx.x + 256 * k;   // 0..2047
        int r = u >> 5;                  // tile row 0..63
        int f = u & 31;                  // col unit 0..31
        float4 val = buf[r * ROWU + f];
        out4[(size_t)(bt * BT + r) * row_u + col0 + f] = val;
    }
}

extern "C" void kernel_launch(void* const* d_in, const int* in_sizes, int n_in,
                              void* d_out, int out_size, void* d_ws, size_t ws_size,
                              hipStream_t stream) {
    const float* X = (const float*)d_in[0];
    const float* P = (const float*)d_in[1];
    float* out = (float*)d_out;

    const int grid = (BATCH / BT) * (GROUPS / GT);  // 128 * 32 = 4096
    hoact_kernel<<<grid, 256, 0, stream>>>(X, P, out);
}

// Round 4
// 46.397 us; speedup vs baseline: 1.7430x; 1.0634x over previous
//
#include <hip/hip_runtime.h>

#define BATCH  8192
#define GROUPS 512
#define OUT_D  8
#define BT     64     // batch rows per block (= lanes per wave)
#define GT     16     // groups per block (4 waves x 4 groups)
#define NGT    (GROUPS / GT)   // 32 group tiles

// Block = 256 threads = 4 waves. Wave w handles groups gt*16+w*4 .. +3 for 64
// consecutive batch rows (lane = batch row): every param-gather instruction's
// 64 lanes hit the SAME group's 864B region.
//
// gt = blockIdx.x % 32: co-resident blocks on a CU (blockIdx stride 256, a
// multiple of 32) all share ONE 13.8KB param tile -> params stay L1-resident
// for the CU's whole lifetime -> gathers are L1 hits, not L2 round-trips.
//
// LDS is exactly 32KB (5 blocks/CU): output staging uses an XOR swizzle
// (f ^ (r&7)) instead of a +1 pad for the same bank spread.
__global__ __launch_bounds__(256) void hoact_kernel(
    const float* __restrict__ X,
    const float* __restrict__ P,
    float* __restrict__ out)
{
    __shared__ float4 buf[BT * 32];      // 64*32*16B = 32 KB exactly
    float* xs = (float*)buf;             // phase 0/1a: xs[c*65 + r], c<48, r<64 (12.5KB)

    const int gt = blockIdx.x % NGT;     // group tile 0..31  (L1 residency key)
    const int bt = blockIdx.x / NGT;     // batch tile 0..127

    const int lane = threadIdx.x & 63;
    const int w    = threadIdx.x >> 6;   // wave id 0..3

    // ---- phase 0: coalesced X tile load + transpose into LDS ----
    const float4* X4 = (const float4*)X;
    const size_t xrow_u = GROUPS * 3 / 4;            // 384 float4 per X row
    #pragma unroll
    for (int k = 0; k < 3; ++k) {
        int m  = threadIdx.x + 256 * k;              // 0..767
        int r  = m / 12;
        int c4 = m % 12;
        float4 v = X4[(size_t)(bt * BT + r) * xrow_u + (size_t)gt * 12 + c4];
        xs[(c4 * 4 + 0) * 65 + r] = v.x;
        xs[(c4 * 4 + 1) * 65 + r] = v.y;
        xs[(c4 * 4 + 2) * 65 + r] = v.z;
        xs[(c4 * 4 + 3) * 65 + r] = v.w;
    }
    __syncthreads();

    // ---- phase 1a: pull this thread's 12 X values ----
    float a[12];
    #pragma unroll
    for (int c = 0; c < 12; ++c)
        a[c] = xs[(w * 12 + c) * 65 + lane];
    __syncthreads();    // xs dead; buf becomes output staging

    // ---- phase 1b: compute + stage output (XOR-swizzled units) ----
    const int gbase = gt * GT + w * 4;
    #pragma unroll
    for (int gi = 0; gi < 4; ++gi) {
        float x0 = a[gi*3+0], x1 = a[gi*3+1], x2 = a[gi*3+2];
        float b0 = fabsf(x0), b1 = fabsf(x1), b2 = fabsf(x2);
        int t0 = (x0 >= 0.f) ? 1 : -1;
        int t1 = (x1 >= 0.f) ? 3 : -3;
        int t2 = (x2 >= 0.f) ? 9 : -9;
        // sort ascending by |x| (ties don't affect the result)
        if (b0 > b1) { float tb=b0; b0=b1; b1=tb; int tt=t0; t0=t1; t1=tt; }
        if (b1 > b2) { float tb=b1; b1=b2; b2=tb; int tt=t1; t1=t2; t2=tt; }
        if (b0 > b1) { float tb=b0; b0=b1; b1=tb; int tt=t0; t0=t1; t1=tt; }
        int i2 = t2 + 13;
        int i1 = t1 + t2 + 13;
        int i0 = t0 + t1 + t2 + 13;
        float c0 = b0;
        float c1 = b1 - b0;
        float c2 = b2 - b1;

        // all 64 lanes share this group -> gathers stay within one 864B
        // region that is L1-resident for the CU's lifetime
        const float* pg = P + (size_t)(gbase + gi) * (27 * OUT_D);
        const float4* p0 = (const float4*)(pg + i0 * OUT_D);
        const float4* p1 = (const float4*)(pg + i1 * OUT_D);
        const float4* p2 = (const float4*)(pg + i2 * OUT_D);
        float4 q0l = p0[0], q0h = p0[1];
        float4 q1l = p1[0], q1h = p1[1];
        float4 q2l = p2[0], q2h = p2[1];

        float4 lo, hi;
        lo.x = c0*q0l.x + c1*q1l.x + c2*q2l.x;
        lo.y = c0*q0l.y + c1*q1l.y + c2*q2l.y;
        lo.z = c0*q0l.z + c1*q1l.z + c2*q2l.z;
        lo.w = c0*q0l.w + c1*q1l.w + c2*q2l.w;
        hi.x = c0*q0h.x + c1*q1h.x + c2*q2h.x;
        hi.y = c0*q0h.y + c1*q1h.y + c2*q2h.y;
        hi.z = c0*q0h.z + c1*q1h.z + c2*q2h.z;
        hi.w = c0*q0h.w + c1*q1h.w + c2*q2h.w;

        int f0 = (w * 4 + gi) * 2;
        int sw = lane & 7;
        buf[lane * 32 + ((f0    ) ^ sw)] = lo;
        buf[lane * 32 + ((f0 + 1) ^ sw)] = hi;
    }
    __syncthreads();

    // ---- phase 2: store 64 rows x 128 floats, lanes contiguous along group ----
    float4* out4 = (float4*)out;
    const size_t row_u = GROUPS * OUT_D / 4;            // 1024 float4 per out row
    const size_t col0  = (size_t)gt * GT * OUT_D / 4;   // 32-unit col offset
    #pragma unroll
    for (int k = 0; k < 8; ++k) {
        int u = threadIdx.x + 256 * k;   // 0..2047
        int r = u >> 5;                  // tile row 0..63
        int f = u & 31;                  // col unit 0..31
        float4 val = buf[r * 32 + (f ^ (r & 7))];
        out4[(size_t)(bt * BT + r) * row_u + col0 + f] = val;
    }
}

extern "C" void kernel_launch(void* const* d_in, const int* in_sizes, int n_in,
                              void* d_out, int out_size, void* d_ws, size_t ws_size,
                              hipStream_t stream) {
    const float* X = (const float*)d_in[0];
    const float* P = (const float*)d_in[1];
    float* out = (float*)d_out;

    const int grid = (BATCH / BT) * NGT;  // 128 * 32 = 4096
    hoact_kernel<<<grid, 256, 0, stream>>>(X, P, out);
}